// Round 6
// baseline (141.738 us; speedup 1.0000x reference)
//
#include <hip/hip_runtime.h>
#include <hip/hip_bf16.h>

typedef __bf16 bf16_8 __attribute__((ext_vector_type(8)));
typedef _Float16 f16x8 __attribute__((ext_vector_type(8)));
typedef float f32x4 __attribute__((ext_vector_type(4)));
typedef float f32x16 __attribute__((ext_vector_type(16)));

#define MFMA_BF(A, B, C)  __builtin_amdgcn_mfma_f32_16x16x32_bf16(A, B, C, 0, 0, 0)
#define MFMA32_F16(A, B, C) __builtin_amdgcn_mfma_f32_32x32x16_f16(A, B, C, 0, 0, 0)
#define MFMA32_BF(A, B, C)  __builtin_amdgcn_mfma_f32_32x32x16_bf16(A, B, C, 0, 0, 0)

#define BATCH 8
#define NPOS 4096            // 64*64 spatial
#define CIN 256
#define CMID 64
#define OC 256
#define NROWS (BATCH * NPOS) // 32768
#define NSPLIT 4             // j-range split for flash parallelism
#define LOG2E 1.44269504088896f

// lane i <-> lane i+32 register swap (hi half of a <-> lo half of b)
__device__ inline void swaplane32(unsigned& a, unsigned& b) {
    asm volatile("v_permlane32_swap_b32 %0, %1" : "+v"(a), "+v"(b));
}

// ---------------------------------------------------------------------------
// proj_kernel (fused): k,q,v = x @ {Wk,Wq,Wv}. x read ONCE into registers
// (bf16 hi/lo pairs), W staged hi/lo in LDS. k,q: split-precision 3-term
// MFMA (fp32-accurate ~1e-4), stored fp16. Wk pre-scaled by log2e so flash
// can use exp2 directly. v: single-term bf16 MFMA (output is bf16-rounded
// anyway), stored transposed vT[b][cv][n]. grid 512, block 256.
// ---------------------------------------------------------------------------
__global__ __launch_bounds__(256) void proj_kernel(
    const float* __restrict__ x,
    const float* __restrict__ Wk, const float* __restrict__ Wq,
    const float* __restrict__ Wv,
    _Float16* __restrict__ k_ws, _Float16* __restrict__ q_ws,
    __bf16* __restrict__ vT_ws)
{
    const int r0 = blockIdx.x * 64;

    __shared__ __bf16 wth[64][264];
    __shared__ __bf16 wtl[64][264];

    const int lane = threadIdx.x & 63;
    const int wv = threadIdx.x >> 6;
    const int kbase = ((lane >> 4) & 3) * 8;
    const int arow = r0 + wv * 16 + (lane & 15);
    const float* xrow = x + (size_t)arow * CIN;

    // x tile -> registers, split hi/lo
    bf16_8 ah[8], al[8];
    #pragma unroll
    for (int kk = 0; kk < 8; ++kk) {
        const float4* xp = (const float4*)(xrow + kk * 32 + kbase);
        float4 x0 = xp[0], x1 = xp[1];
        float xs[8] = {x0.x, x0.y, x0.z, x0.w, x1.x, x1.y, x1.z, x1.w};
        #pragma unroll
        for (int e = 0; e < 8; ++e) {
            __bf16 h = (__bf16)xs[e];
            ah[kk][e] = h;
            al[kk][e] = (__bf16)(xs[e] - (float)h);
        }
    }

    const float* Ws[3] = {Wk, Wq, Wv};
    const int rrow = r0 + wv * 16 + ((lane >> 4) & 3) * 4;

    for (int m = 0; m < 3; ++m) {
        __syncthreads();   // previous iteration's LDS reads complete
        const float wscale = (m == 0) ? LOG2E : 1.0f;
        for (int idx = threadIdx.x; idx < 64 * 256; idx += 256) {
            int col = idx & 63, k = idx >> 6;
            float f = Ws[m][k * 64 + col] * wscale;
            __bf16 h = (__bf16)f;
            wth[col][k] = h;
            if (m < 2) wtl[col][k] = (__bf16)(f - (float)h);
        }
        __syncthreads();

        f32x4 acc[4] = {f32x4{0,0,0,0}, f32x4{0,0,0,0}, f32x4{0,0,0,0}, f32x4{0,0,0,0}};
        if (m < 2) {
            #pragma unroll
            for (int kk = 0; kk < 8; ++kk) {
                #pragma unroll
                for (int nt = 0; nt < 4; ++nt) {
                    bf16_8 bh = *(const bf16_8*)&wth[(lane & 15) + 16 * nt][kk * 32 + kbase];
                    bf16_8 bl = *(const bf16_8*)&wtl[(lane & 15) + 16 * nt][kk * 32 + kbase];
                    acc[nt] = MFMA_BF(ah[kk], bh, acc[nt]);
                    acc[nt] = MFMA_BF(ah[kk], bl, acc[nt]);
                    acc[nt] = MFMA_BF(al[kk], bh, acc[nt]);
                }
            }
        } else {
            #pragma unroll
            for (int kk = 0; kk < 8; ++kk) {
                #pragma unroll
                for (int nt = 0; nt < 4; ++nt) {
                    bf16_8 bh = *(const bf16_8*)&wth[(lane & 15) + 16 * nt][kk * 32 + kbase];
                    acc[nt] = MFMA_BF(ah[kk], bh, acc[nt]);
                }
            }
        }

        if (m < 2) {
            _Float16* dst = (m == 0) ? k_ws : q_ws;
            #pragma unroll
            for (int nt = 0; nt < 4; ++nt)
                #pragma unroll
                for (int r = 0; r < 4; ++r)
                    dst[(size_t)(rrow + r) * CMID + (lane & 15) + 16 * nt] =
                        (_Float16)acc[nt][r];
        } else {
            const int b = rrow >> 12;
            const int n = rrow & (NPOS - 1);
            #pragma unroll
            for (int nt = 0; nt < 4; ++nt) {
                int cv = (lane & 15) + 16 * nt;
                union { __bf16 h[4]; uint2 u; } pk;
                #pragma unroll
                for (int r = 0; r < 4; ++r) pk.h[r] = (__bf16)acc[nt][r];
                *(uint2*)(vT_ws + ((size_t)b * CMID + cv) * NPOS + n) = pk.u;
            }
        }
    }
}

// ---------------------------------------------------------------------------
// flash_kernel: streaming attention, 32x32 swapped-QK^T, in-register P,
// 64 i-rows per wave (2 i-sets sharing every LDS read), double-buffered
// tiles with issue-early/write-late staging. k pre-scaled by log2e ->
// p = exp2(s). Writes unnormalized partial numerators + denominators.
// grid (16, 8, NSPLIT): 256-row i-tile, batch, j-split. 4 waves/block.
// ---------------------------------------------------------------------------
#define ISTEP(KF, O0, O1, DEN)                                              \
    do {                                                                    \
        f32x16 s = {0,0,0,0,0,0,0,0,0,0,0,0,0,0,0,0};                       \
        s = MFMA32_F16(aq[0], KF[0], s);                                    \
        s = MFMA32_F16(aq[1], KF[1], s);                                    \
        s = MFMA32_F16(aq[2], KF[2], s);                                    \
        s = MFMA32_F16(aq[3], KF[3], s);                                    \
        unsigned pk[8];                                                     \
        _Pragma("unroll")                                                   \
        for (int m = 0; m < 8; ++m) {                                       \
            float p0 = exp2f(s[2 * m]);                                     \
            float p1 = exp2f(s[2 * m + 1]);                                 \
            DEN += p0 + p1;                                                 \
            union { __bf16 h[2]; unsigned u; } w;                           \
            w.h[0] = (__bf16)p0; w.h[1] = (__bf16)p1;                       \
            pk[m] = w.u;                                                    \
        }                                                                   \
        swaplane32(pk[0], pk[2]); swaplane32(pk[1], pk[3]);                 \
        swaplane32(pk[4], pk[6]); swaplane32(pk[5], pk[7]);                 \
        union { unsigned u[4]; bf16_8 v; } pa0, pa1;                        \
        pa0.u[0] = pk[0]; pa0.u[1] = pk[1]; pa0.u[2] = pk[2]; pa0.u[3] = pk[3]; \
        pa1.u[0] = pk[4]; pa1.u[1] = pk[5]; pa1.u[2] = pk[6]; pa1.u[3] = pk[7]; \
        O0 = MFMA32_BF(pa0.v, bv00, O0);                                    \
        O0 = MFMA32_BF(pa1.v, bv01, O0);                                    \
        O1 = MFMA32_BF(pa0.v, bv10, O1);                                    \
        O1 = MFMA32_BF(pa1.v, bv11, O1);                                    \
    } while (0)

__global__ __launch_bounds__(256, 2) void flash_kernel(
    const _Float16* __restrict__ k_ws,  // [32768][64]
    const _Float16* __restrict__ q_ws,  // [32768][64]
    const __bf16* __restrict__ vT_ws,   // [8][64][4096]
    __bf16* __restrict__ po,            // [NSPLIT][32768][64]
    float* __restrict__ pden)           // [NSPLIT][32768]
{
    const int b = blockIdx.y;
    const int i0 = blockIdx.x * 256;
    const int sblk = blockIdx.z;
    const int jbase = sblk * (NPOS / NSPLIT);
    const int lane = threadIdx.x & 63;
    const int wv = threadIdx.x >> 6;
    const int l31 = lane & 31;
    const int g = lane >> 5;

    __shared__ _Float16 qt[2][64][72];
    __shared__ __bf16 vt[2][64][72];

    // two i-sets of k B-fragments (64 i-rows per wave)
    f16x8 kf[2][4];
    #pragma unroll
    for (int is = 0; is < 2; ++is) {
        const _Float16* kp =
            k_ws + ((size_t)(b * NPOS + i0 + wv * 64 + is * 32 + l31)) * CMID + g * 8;
        #pragma unroll
        for (int c = 0; c < 4; ++c) kf[is][c] = *(const f16x8*)(kp + c * 16);
    }

    f32x16 o00 = {0,0,0,0,0,0,0,0,0,0,0,0,0,0,0,0};
    f32x16 o01 = {0,0,0,0,0,0,0,0,0,0,0,0,0,0,0,0};
    f32x16 o10 = {0,0,0,0,0,0,0,0,0,0,0,0,0,0,0,0};
    f32x16 o11 = {0,0,0,0,0,0,0,0,0,0,0,0,0,0,0,0};
    float den0 = 0.f, den1 = 0.f;

    const int r = threadIdx.x >> 2, c0 = (threadIdx.x & 3) * 16;
    uint4 nq0, nq1, nv0, nv1;

    // prologue: tile 0
    {
        const _Float16* qs = q_ws + ((size_t)(b * NPOS + jbase + r)) * CMID + c0;
        nq0 = ((const uint4*)qs)[0]; nq1 = ((const uint4*)qs)[1];
        const __bf16* vs = vT_ws + ((size_t)b * CMID + r) * NPOS + jbase + c0;
        nv0 = ((const uint4*)vs)[0]; nv1 = ((const uint4*)vs)[1];
        *(uint4*)&qt[0][r][c0] = nq0; *(uint4*)&qt[0][r][c0 + 8] = nq1;
        *(uint4*)&vt[0][r][c0] = nv0; *(uint4*)&vt[0][r][c0 + 8] = nv1;
    }
    __syncthreads();

    const int NT = (NPOS / NSPLIT) / 64;  // 16
    for (int t = 0; t < NT; ++t) {
        const int cur = t & 1;
        if (t + 1 < NT) {   // issue next-tile loads early (latency hides under MFMA)
            int j1 = jbase + (t + 1) * 64;
            const _Float16* qs = q_ws + ((size_t)(b * NPOS + j1 + r)) * CMID + c0;
            nq0 = ((const uint4*)qs)[0]; nq1 = ((const uint4*)qs)[1];
            const __bf16* vs = vT_ws + ((size_t)b * CMID + r) * NPOS + j1 + c0;
            nv0 = ((const uint4*)vs)[0]; nv1 = ((const uint4*)vs)[1];
        }

        #pragma unroll
        for (int jj = 0; jj < 2; ++jj) {
            f16x8 aq[4];
            #pragma unroll
            for (int c = 0; c < 4; ++c)
                aq[c] = *(const f16x8*)&qt[cur][jj * 32 + l31][c * 16 + g * 8];
            bf16_8 bv00 = *(const bf16_8*)&vt[cur][l31][jj * 32 + g * 8];
            bf16_8 bv01 = *(const bf16_8*)&vt[cur][l31][jj * 32 + 16 + g * 8];
            bf16_8 bv10 = *(const bf16_8*)&vt[cur][32 + l31][jj * 32 + g * 8];
            bf16_8 bv11 = *(const bf16_8*)&vt[cur][32 + l31][jj * 32 + 16 + g * 8];

            ISTEP(kf[0], o00, o01, den0);
            ISTEP(kf[1], o10, o11, den1);
        }

        if (t + 1 < NT) {   // write-late into the other buffer
            const int nb = cur ^ 1;
            *(uint4*)&qt[nb][r][c0] = nq0; *(uint4*)&qt[nb][r][c0 + 8] = nq1;
            *(uint4*)&vt[nb][r][c0] = nv0; *(uint4*)&vt[nb][r][c0 + 8] = nv1;
        }
        __syncthreads();
    }

    den0 += __shfl_xor(den0, 32);
    den1 += __shfl_xor(den1, 32);

    const size_t rowb = (size_t)b * NPOS + i0 + wv * 64;
    if (lane < 32) {
        pden[(size_t)sblk * NROWS + rowb + lane] = den0;
        pden[(size_t)sblk * NROWS + rowb + 32 + lane] = den1;
    }

    #pragma unroll
    for (int reg = 0; reg < 16; ++reg) {
        int il = (reg & 3) + 8 * (reg >> 2) + 4 * g;
        size_t base0 = ((size_t)sblk * NROWS + rowb + il) * CMID + l31;
        po[base0]      = (__bf16)o00[reg];
        po[base0 + 32] = (__bf16)o01[reg];
        size_t base1 = ((size_t)sblk * NROWS + rowb + 32 + il) * CMID + l31;
        po[base1]      = (__bf16)o10[reg];
        po[base1 + 32] = (__bf16)o11[reg];
    }
}

// ---------------------------------------------------------------------------
// out_kernel: combine j-split partials (normalize, bf16) + MFMA attn @ Wo
// + fused BatchNorm. Wo B-fragments loaded straight from global (L2-hot).
// grid 2048, block 256 (4 waves, wave wv owns output cols wv*64..+63).
// ---------------------------------------------------------------------------
__global__ __launch_bounds__(256) void out_kernel(
    const __bf16* __restrict__ po,      // [NSPLIT][32768][64]
    const float* __restrict__ pden,     // [NSPLIT][32768]
    const float* __restrict__ Wo,       // [64][256]
    const float* __restrict__ gamma, const float* __restrict__ beta,
    const float* __restrict__ mmean, const float* __restrict__ mvar,
    float* __restrict__ out)            // [32768][256]
{
    const int r0 = blockIdx.x * 16;
    const int t = threadIdx.x;
    const int lane = t & 63;
    const int wv = t >> 6;
    const int n0 = wv * 64;

    __shared__ __bf16 at[16][72];
    __shared__ float dinv[16];

    // Wo B-fragments from global, bf16 cast (issued early, L2-hot)
    bf16_8 wb[4][2];
    #pragma unroll
    for (int nt = 0; nt < 4; ++nt) {
        int col = n0 + nt * 16 + (lane & 15);
        #pragma unroll
        for (int ch = 0; ch < 2; ++ch)
            #pragma unroll
            for (int e = 0; e < 8; ++e)
                wb[nt][ch][e] = (__bf16)Wo[(ch * 32 + (lane >> 4) * 8 + e) * OC + col];
    }

    if (t < 16) {
        float d = 0.f;
        #pragma unroll
        for (int s = 0; s < NSPLIT; ++s) d += pden[(size_t)s * NROWS + r0 + t];
        dinv[t] = 1.0f / d;
    }
    __syncthreads();

    for (int idx = t; idx < 16 * 64; idx += 256) {
        int rr = idx >> 6, c = idx & 63;
        float sum = 0.f;
        #pragma unroll
        for (int s = 0; s < NSPLIT; ++s)
            sum += (float)po[((size_t)s * NROWS + r0 + rr) * CMID + c];
        at[rr][c] = (__bf16)(sum * dinv[rr]);
    }
    __syncthreads();

    bf16_8 a0 = *(const bf16_8*)&at[lane & 15][(lane >> 4) * 8];
    bf16_8 a1 = *(const bf16_8*)&at[lane & 15][32 + (lane >> 4) * 8];

    #pragma unroll
    for (int nt = 0; nt < 4; ++nt) {
        int col = n0 + nt * 16 + (lane & 15);
        f32x4 acc = {0.f, 0.f, 0.f, 0.f};
        acc = MFMA_BF(a0, wb[nt][0], acc);
        acc = MFMA_BF(a1, wb[nt][1], acc);
        float sc = gamma[col] * rsqrtf(mvar[col] + 1e-3f);
        float sh = beta[col] - mmean[col] * sc;
        int rl = (lane >> 4) * 4;
        #pragma unroll
        for (int rr = 0; rr < 4; ++rr)
            out[(size_t)(r0 + rl + rr) * OC + col] = acc[rr] * sc + sh;
    }
}

// ---------------------------------------------------------------------------
extern "C" void kernel_launch(void* const* d_in, const int* in_sizes, int n_in,
                              void* d_out, int out_size, void* d_ws, size_t ws_size,
                              hipStream_t stream) {
    const float* x     = (const float*)d_in[0];
    const float* Wk    = (const float*)d_in[1];
    const float* Wq    = (const float*)d_in[2];
    const float* Wv    = (const float*)d_in[3];
    const float* Wo    = (const float*)d_in[4];
    const float* gamma = (const float*)d_in[5];
    const float* beta  = (const float*)d_in[6];
    const float* mmean = (const float*)d_in[7];
    const float* mvar  = (const float*)d_in[8];
    float* out = (float*)d_out;

    // k/q/vT live in d_out (33.5 MB): dead before out_kernel writes out.
    char* ob = (char*)d_out;
    const size_t MB4 = (size_t)NROWS * CMID * 2;   // 4 MiB
    _Float16* k_ws = (_Float16*)ob;                // 4 MiB
    _Float16* q_ws = (_Float16*)(ob + MB4);        // 4 MiB
    __bf16*   vT   = (__bf16*)(ob + 2 * MB4);      // 4 MiB

    __bf16* po   = (__bf16*)d_ws;                                // 16 MiB
    float*  pden = (float*)((char*)d_ws + (size_t)NSPLIT * MB4); // 512 KiB

    proj_kernel<<<512, 256, 0, stream>>>(x, Wk, Wq, Wv, k_ws, q_ws, vT);
    flash_kernel<<<dim3(16, 8, NSPLIT), 256, 0, stream>>>(k_ws, q_ws, vT, po, pden);
    out_kernel<<<2048, 256, 0, stream>>>(po, pden, Wo, gamma, beta, mmean, mvar, out);
}

// Round 7
// 99.317 us; speedup vs baseline: 1.4271x; 1.4271x over previous
//
#include <hip/hip_runtime.h>
#include <hip/hip_bf16.h>

typedef __bf16 bf16_8 __attribute__((ext_vector_type(8)));
typedef _Float16 f16x8 __attribute__((ext_vector_type(8)));
typedef float f32x4 __attribute__((ext_vector_type(4)));
typedef float f32x16 __attribute__((ext_vector_type(16)));

#define MFMA_BF(A, B, C)    __builtin_amdgcn_mfma_f32_16x16x32_bf16(A, B, C, 0, 0, 0)
#define MFMA_F16(A, B, C)   __builtin_amdgcn_mfma_f32_16x16x32_f16(A, B, C, 0, 0, 0)
#define MFMA32_F16(A, B, C) __builtin_amdgcn_mfma_f32_32x32x16_f16(A, B, C, 0, 0, 0)
#define MFMA32_BF(A, B, C)  __builtin_amdgcn_mfma_f32_32x32x16_bf16(A, B, C, 0, 0, 0)

#define BATCH 8
#define NPOS 4096            // 64*64 spatial
#define CIN 256
#define CMID 64
#define OC 256
#define NROWS (BATCH * NPOS) // 32768
#define NSPLIT 4             // j-range split for flash parallelism
#define LOG2E 1.44269504088896f

// lane i <-> lane i+32 register swap (hi half of a <-> lo half of b)
__device__ inline void swaplane32(unsigned& a, unsigned& b) {
    asm volatile("v_permlane32_swap_b32 %0, %1" : "+v"(a), "+v"(b));
}

// ---------------------------------------------------------------------------
// proj_kernel: one of {k,q,v} = x @ W (M=32768, K=256, N=64), all-fp16
// inputs (error ~2^-11 rel — budgeted). Wk pre-scaled by log2e so flash
// uses exp2 directly. grid (512, 3), block 256, ONE barrier phase.
// LDS: wt[64][266] fp16 = 34 KB -> 4 blocks/CU. 266-pad => odd dword row
// stride (133) => staging writes and fragment reads conflict-free.
// k,q written via LDS repack -> coalesced uint4 stores. v -> vT bf16.
// ---------------------------------------------------------------------------
__global__ __launch_bounds__(256) void proj_kernel(
    const float* __restrict__ x,
    const float* __restrict__ Wk, const float* __restrict__ Wq,
    const float* __restrict__ Wv,
    _Float16* __restrict__ k_ws, _Float16* __restrict__ q_ws,
    __bf16* __restrict__ vT_ws)
{
    const int m = blockIdx.y;
    const int r0 = blockIdx.x * 64;
    const float* W = (m == 0) ? Wk : (m == 1) ? Wq : Wv;
    const float wscale = (m == 0) ? LOG2E : 1.0f;

    __shared__ _Float16 wt[64][266];   // W^T [col][k]

    // stage W^T (coalesced global read, <=2-way LDS banks)
    for (int idx = threadIdx.x; idx < 64 * 256; idx += 256) {
        int col = idx & 63, k = idx >> 6;
        wt[col][k] = (_Float16)(W[k * 64 + col] * wscale);
    }

    const int lane = threadIdx.x & 63;
    const int wv = threadIdx.x >> 6;
    const int kbase = ((lane >> 4) & 3) * 8;
    const int arow = r0 + wv * 16 + (lane & 15);
    const float* xrow = x + (size_t)arow * CIN;

    // x tile -> fp16 registers
    f16x8 a[8];
    #pragma unroll
    for (int kk = 0; kk < 8; ++kk) {
        const float4* xp = (const float4*)(xrow + kk * 32 + kbase);
        float4 x0 = xp[0], x1 = xp[1];
        float xs[8] = {x0.x, x0.y, x0.z, x0.w, x1.x, x1.y, x1.z, x1.w};
        #pragma unroll
        for (int e = 0; e < 8; ++e) a[kk][e] = (_Float16)xs[e];
    }
    __syncthreads();

    f32x4 acc[4] = {f32x4{0,0,0,0}, f32x4{0,0,0,0}, f32x4{0,0,0,0}, f32x4{0,0,0,0}};
    #pragma unroll
    for (int kk = 0; kk < 8; ++kk) {
        #pragma unroll
        for (int nt = 0; nt < 4; ++nt) {
            f16x8 b = *(const f16x8*)&wt[(lane & 15) + 16 * nt][kk * 32 + kbase];
            acc[nt] = MFMA_F16(a[kk], b, acc[nt]);
        }
    }

    const int rloc = wv * 16 + ((lane >> 4) & 3) * 4;   // local row base of frag
    if (m < 2) {
        // repack through LDS (reuse wt) -> coalesced 16B stores
        __syncthreads();                   // all wt fragment reads done
        _Float16* rp = &wt[0][0];          // viewed as [64][72]
        #pragma unroll
        for (int nt = 0; nt < 4; ++nt)
            #pragma unroll
            for (int r = 0; r < 4; ++r)
                rp[(rloc + r) * 72 + (lane & 15) + 16 * nt] = (_Float16)acc[nt][r];
        __syncthreads();
        _Float16* dst = (m == 0) ? k_ws : q_ws;
        const int row = threadIdx.x >> 3, c0 = (threadIdx.x & 7) * 8;
        #pragma unroll
        for (int h = 0; h < 2; ++h) {
            uint4 v = *(const uint4*)&rp[(row + 32 * h) * 72 + c0];
            *(uint4*)(dst + (size_t)(r0 + row + 32 * h) * CMID + c0) = v;
        }
    } else {
        const int rrow = r0 + rloc;
        const int b = rrow >> 12;
        const int n = rrow & (NPOS - 1);
        #pragma unroll
        for (int nt = 0; nt < 4; ++nt) {
            int cv = (lane & 15) + 16 * nt;
            union { __bf16 h[4]; uint2 u; } pk;
            #pragma unroll
            for (int r = 0; r < 4; ++r) pk.h[r] = (__bf16)acc[nt][r];
            *(uint2*)(vT_ws + ((size_t)b * CMID + cv) * NPOS + n) = pk.u;
        }
    }
}

// ---------------------------------------------------------------------------
// flash_kernel: streaming attention, 32x32 swapped-QK^T, in-register P,
// 64 i-rows per wave (2 i-sets sharing every LDS read), double-buffered
// tiles with issue-early/write-late staging. k pre-scaled by log2e ->
// p = exp2(s). Writes unnormalized partial numerators + denominators.
// grid (16, 8, NSPLIT): 256-row i-tile, batch, j-split. 4 waves/block.
// ---------------------------------------------------------------------------
#define ISTEP(KF, O0, O1, DEN)                                              \
    do {                                                                    \
        f32x16 s = {0,0,0,0,0,0,0,0,0,0,0,0,0,0,0,0};                       \
        s = MFMA32_F16(aq[0], KF[0], s);                                    \
        s = MFMA32_F16(aq[1], KF[1], s);                                    \
        s = MFMA32_F16(aq[2], KF[2], s);                                    \
        s = MFMA32_F16(aq[3], KF[3], s);                                    \
        unsigned pk[8];                                                     \
        _Pragma("unroll")                                                   \
        for (int m = 0; m < 8; ++m) {                                       \
            float p0 = exp2f(s[2 * m]);                                     \
            float p1 = exp2f(s[2 * m + 1]);                                 \
            DEN += p0 + p1;                                                 \
            union { __bf16 h[2]; unsigned u; } w;                           \
            w.h[0] = (__bf16)p0; w.h[1] = (__bf16)p1;                       \
            pk[m] = w.u;                                                    \
        }                                                                   \
        swaplane32(pk[0], pk[2]); swaplane32(pk[1], pk[3]);                 \
        swaplane32(pk[4], pk[6]); swaplane32(pk[5], pk[7]);                 \
        union { unsigned u[4]; bf16_8 v; } pa0, pa1;                        \
        pa0.u[0] = pk[0]; pa0.u[1] = pk[1]; pa0.u[2] = pk[2]; pa0.u[3] = pk[3]; \
        pa1.u[0] = pk[4]; pa1.u[1] = pk[5]; pa1.u[2] = pk[6]; pa1.u[3] = pk[7]; \
        O0 = MFMA32_BF(pa0.v, bv00, O0);                                    \
        O0 = MFMA32_BF(pa1.v, bv01, O0);                                    \
        O1 = MFMA32_BF(pa0.v, bv10, O1);                                    \
        O1 = MFMA32_BF(pa1.v, bv11, O1);                                    \
    } while (0)

__global__ __launch_bounds__(256, 2) void flash_kernel(
    const _Float16* __restrict__ k_ws,  // [32768][64]
    const _Float16* __restrict__ q_ws,  // [32768][64]
    const __bf16* __restrict__ vT_ws,   // [8][64][4096]
    __bf16* __restrict__ po,            // [NSPLIT][32768][64]
    float* __restrict__ pden)           // [NSPLIT][32768]
{
    const int b = blockIdx.y;
    const int i0 = blockIdx.x * 256;
    const int sblk = blockIdx.z;
    const int jbase = sblk * (NPOS / NSPLIT);
    const int lane = threadIdx.x & 63;
    const int wv = threadIdx.x >> 6;
    const int l31 = lane & 31;
    const int g = lane >> 5;

    __shared__ _Float16 qt[2][64][72];
    __shared__ __bf16 vt[2][64][72];

    // two i-sets of k B-fragments (64 i-rows per wave)
    f16x8 kf[2][4];
    #pragma unroll
    for (int is = 0; is < 2; ++is) {
        const _Float16* kp =
            k_ws + ((size_t)(b * NPOS + i0 + wv * 64 + is * 32 + l31)) * CMID + g * 8;
        #pragma unroll
        for (int c = 0; c < 4; ++c) kf[is][c] = *(const f16x8*)(kp + c * 16);
    }

    f32x16 o00 = {0,0,0,0,0,0,0,0,0,0,0,0,0,0,0,0};
    f32x16 o01 = {0,0,0,0,0,0,0,0,0,0,0,0,0,0,0,0};
    f32x16 o10 = {0,0,0,0,0,0,0,0,0,0,0,0,0,0,0,0};
    f32x16 o11 = {0,0,0,0,0,0,0,0,0,0,0,0,0,0,0,0};
    float den0 = 0.f, den1 = 0.f;

    const int r = threadIdx.x >> 2, c0 = (threadIdx.x & 3) * 16;
    uint4 nq0, nq1, nv0, nv1;

    // prologue: tile 0
    {
        const _Float16* qs = q_ws + ((size_t)(b * NPOS + jbase + r)) * CMID + c0;
        nq0 = ((const uint4*)qs)[0]; nq1 = ((const uint4*)qs)[1];
        const __bf16* vs = vT_ws + ((size_t)b * CMID + r) * NPOS + jbase + c0;
        nv0 = ((const uint4*)vs)[0]; nv1 = ((const uint4*)vs)[1];
        *(uint4*)&qt[0][r][c0] = nq0; *(uint4*)&qt[0][r][c0 + 8] = nq1;
        *(uint4*)&vt[0][r][c0] = nv0; *(uint4*)&vt[0][r][c0 + 8] = nv1;
    }
    __syncthreads();

    const int NT = (NPOS / NSPLIT) / 64;  // 16
    for (int t = 0; t < NT; ++t) {
        const int cur = t & 1;
        if (t + 1 < NT) {   // issue next-tile loads early (latency hides under MFMA)
            int j1 = jbase + (t + 1) * 64;
            const _Float16* qs = q_ws + ((size_t)(b * NPOS + j1 + r)) * CMID + c0;
            nq0 = ((const uint4*)qs)[0]; nq1 = ((const uint4*)qs)[1];
            const __bf16* vs = vT_ws + ((size_t)b * CMID + r) * NPOS + j1 + c0;
            nv0 = ((const uint4*)vs)[0]; nv1 = ((const uint4*)vs)[1];
        }

        #pragma unroll
        for (int jj = 0; jj < 2; ++jj) {
            f16x8 aq[4];
            #pragma unroll
            for (int c = 0; c < 4; ++c)
                aq[c] = *(const f16x8*)&qt[cur][jj * 32 + l31][c * 16 + g * 8];
            bf16_8 bv00 = *(const bf16_8*)&vt[cur][l31][jj * 32 + g * 8];
            bf16_8 bv01 = *(const bf16_8*)&vt[cur][l31][jj * 32 + 16 + g * 8];
            bf16_8 bv10 = *(const bf16_8*)&vt[cur][32 + l31][jj * 32 + g * 8];
            bf16_8 bv11 = *(const bf16_8*)&vt[cur][32 + l31][jj * 32 + 16 + g * 8];

            ISTEP(kf[0], o00, o01, den0);
            ISTEP(kf[1], o10, o11, den1);
        }

        if (t + 1 < NT) {   // write-late into the other buffer
            const int nb = cur ^ 1;
            *(uint4*)&qt[nb][r][c0] = nq0; *(uint4*)&qt[nb][r][c0 + 8] = nq1;
            *(uint4*)&vt[nb][r][c0] = nv0; *(uint4*)&vt[nb][r][c0 + 8] = nv1;
        }
        __syncthreads();
    }

    den0 += __shfl_xor(den0, 32);
    den1 += __shfl_xor(den1, 32);

    const size_t rowb = (size_t)b * NPOS + i0 + wv * 64;
    if (lane < 32) {
        pden[(size_t)sblk * NROWS + rowb + lane] = den0;
        pden[(size_t)sblk * NROWS + rowb + 32 + lane] = den1;
    }

    #pragma unroll
    for (int reg = 0; reg < 16; ++reg) {
        int il = (reg & 3) + 8 * (reg >> 2) + 4 * g;
        size_t base0 = ((size_t)sblk * NROWS + rowb + il) * CMID + l31;
        po[base0]      = (__bf16)o00[reg];
        po[base0 + 32] = (__bf16)o01[reg];
        size_t base1 = ((size_t)sblk * NROWS + rowb + 32 + il) * CMID + l31;
        po[base1]      = (__bf16)o10[reg];
        po[base1 + 32] = (__bf16)o11[reg];
    }
}

// ---------------------------------------------------------------------------
// out_kernel: combine j-split partials (normalize, bf16) + MFMA attn @ Wo
// + fused BatchNorm. Wo B-fragments loaded straight from global (L2-hot).
// grid 2048, block 256 (4 waves, wave wv owns output cols wv*64..+63).
// ---------------------------------------------------------------------------
__global__ __launch_bounds__(256) void out_kernel(
    const __bf16* __restrict__ po,      // [NSPLIT][32768][64]
    const float* __restrict__ pden,     // [NSPLIT][32768]
    const float* __restrict__ Wo,       // [64][256]
    const float* __restrict__ gamma, const float* __restrict__ beta,
    const float* __restrict__ mmean, const float* __restrict__ mvar,
    float* __restrict__ out)            // [32768][256]
{
    const int r0 = blockIdx.x * 16;
    const int t = threadIdx.x;
    const int lane = t & 63;
    const int wv = t >> 6;
    const int n0 = wv * 64;

    __shared__ __bf16 at[16][72];
    __shared__ float dinv[16];

    // Wo B-fragments from global, bf16 cast (issued early, L2-hot)
    bf16_8 wb[4][2];
    #pragma unroll
    for (int nt = 0; nt < 4; ++nt) {
        int col = n0 + nt * 16 + (lane & 15);
        #pragma unroll
        for (int ch = 0; ch < 2; ++ch)
            #pragma unroll
            for (int e = 0; e < 8; ++e)
                wb[nt][ch][e] = (__bf16)Wo[(ch * 32 + (lane >> 4) * 8 + e) * OC + col];
    }

    if (t < 16) {
        float d = 0.f;
        #pragma unroll
        for (int s = 0; s < NSPLIT; ++s) d += pden[(size_t)s * NROWS + r0 + t];
        dinv[t] = 1.0f / d;
    }
    __syncthreads();

    for (int idx = t; idx < 16 * 64; idx += 256) {
        int rr = idx >> 6, c = idx & 63;
        float sum = 0.f;
        #pragma unroll
        for (int s = 0; s < NSPLIT; ++s)
            sum += (float)po[((size_t)s * NROWS + r0 + rr) * CMID + c];
        at[rr][c] = (__bf16)(sum * dinv[rr]);
    }
    __syncthreads();

    bf16_8 a0 = *(const bf16_8*)&at[lane & 15][(lane >> 4) * 8];
    bf16_8 a1 = *(const bf16_8*)&at[lane & 15][32 + (lane >> 4) * 8];

    #pragma unroll
    for (int nt = 0; nt < 4; ++nt) {
        int col = n0 + nt * 16 + (lane & 15);
        f32x4 acc = {0.f, 0.f, 0.f, 0.f};
        acc = MFMA_BF(a0, wb[nt][0], acc);
        acc = MFMA_BF(a1, wb[nt][1], acc);
        float sc = gamma[col] * rsqrtf(mvar[col] + 1e-3f);
        float sh = beta[col] - mmean[col] * sc;
        int rl = (lane >> 4) * 4;
        #pragma unroll
        for (int rr = 0; rr < 4; ++rr)
            out[(size_t)(r0 + rl + rr) * OC + col] = acc[rr] * sc + sh;
    }
}

// ---------------------------------------------------------------------------
extern "C" void kernel_launch(void* const* d_in, const int* in_sizes, int n_in,
                              void* d_out, int out_size, void* d_ws, size_t ws_size,
                              hipStream_t stream) {
    const float* x     = (const float*)d_in[0];
    const float* Wk    = (const float*)d_in[1];
    const float* Wq    = (const float*)d_in[2];
    const float* Wv    = (const float*)d_in[3];
    const float* Wo    = (const float*)d_in[4];
    const float* gamma = (const float*)d_in[5];
    const float* beta  = (const float*)d_in[6];
    const float* mmean = (const float*)d_in[7];
    const float* mvar  = (const float*)d_in[8];
    float* out = (float*)d_out;

    // k/q/vT live in d_out (33.5 MB): dead before out_kernel writes out.
    char* ob = (char*)d_out;
    const size_t MB4 = (size_t)NROWS * CMID * 2;   // 4 MiB
    _Float16* k_ws = (_Float16*)ob;                // 4 MiB
    _Float16* q_ws = (_Float16*)(ob + MB4);        // 4 MiB
    __bf16*   vT   = (__bf16*)(ob + 2 * MB4);      // 4 MiB

    __bf16* po   = (__bf16*)d_ws;                                // 16 MiB
    float*  pden = (float*)((char*)d_ws + (size_t)NSPLIT * MB4); // 512 KiB

    proj_kernel<<<dim3(512, 3), 256, 0, stream>>>(x, Wk, Wq, Wv, k_ws, q_ws, vT);
    flash_kernel<<<dim3(16, 8, NSPLIT), 256, 0, stream>>>(k_ws, q_ws, vT, po, pden);
    out_kernel<<<2048, 256, 0, stream>>>(po, pden, Wo, gamma, beta, mmean, mvar, out);
}

// Round 8
// 98.991 us; speedup vs baseline: 1.4318x; 1.0033x over previous
//
#include <hip/hip_runtime.h>
#include <hip/hip_bf16.h>

typedef __bf16 bf16_8 __attribute__((ext_vector_type(8)));
typedef _Float16 f16x8 __attribute__((ext_vector_type(8)));
typedef float f32x4 __attribute__((ext_vector_type(4)));
typedef float f32x16 __attribute__((ext_vector_type(16)));

#define MFMA_BF(A, B, C)    __builtin_amdgcn_mfma_f32_16x16x32_bf16(A, B, C, 0, 0, 0)
#define MFMA_F16(A, B, C)   __builtin_amdgcn_mfma_f32_16x16x32_f16(A, B, C, 0, 0, 0)
#define MFMA32_F16(A, B, C) __builtin_amdgcn_mfma_f32_32x32x16_f16(A, B, C, 0, 0, 0)
#define MFMA32_BF(A, B, C)  __builtin_amdgcn_mfma_f32_32x32x16_bf16(A, B, C, 0, 0, 0)

#define BATCH 8
#define NPOS 4096            // 64*64 spatial
#define CIN 256
#define CMID 64
#define OC 256
#define NROWS (BATCH * NPOS) // 32768
#define NSPLIT 4             // j-range split for flash parallelism
#define LOG2E 1.44269504088896f

// lane i <-> lane i+32 register swap (hi half of a <-> lo half of b)
__device__ inline void swaplane32(unsigned& a, unsigned& b) {
    asm volatile("v_permlane32_swap_b32 %0, %1" : "+v"(a), "+v"(b));
}

// ---------------------------------------------------------------------------
// proj_kernel: one of {k,q,v} = x @ W (M=32768, K=256, N=64), all-fp16
// inputs (error ~2^-11 rel — budgeted). Wk pre-scaled by log2e so flash
// uses exp2 directly. grid (512, 3), block 256, ONE barrier phase.
// LDS: wt[64][266] fp16 = 34 KB -> 4 blocks/CU. 266-pad => odd dword row
// stride (133) => staging writes and fragment reads conflict-free.
// k,q written via LDS repack -> coalesced uint4 stores. v -> vT bf16.
// ---------------------------------------------------------------------------
__global__ __launch_bounds__(256) void proj_kernel(
    const float* __restrict__ x,
    const float* __restrict__ Wk, const float* __restrict__ Wq,
    const float* __restrict__ Wv,
    _Float16* __restrict__ k_ws, _Float16* __restrict__ q_ws,
    __bf16* __restrict__ vT_ws)
{
    const int m = blockIdx.y;
    const int r0 = blockIdx.x * 64;
    const float* W = (m == 0) ? Wk : (m == 1) ? Wq : Wv;
    const float wscale = (m == 0) ? LOG2E : 1.0f;

    __shared__ _Float16 wt[64][266];   // W^T [col][k]

    // stage W^T (coalesced global read, <=2-way LDS banks)
    for (int idx = threadIdx.x; idx < 64 * 256; idx += 256) {
        int col = idx & 63, k = idx >> 6;
        wt[col][k] = (_Float16)(W[k * 64 + col] * wscale);
    }

    const int lane = threadIdx.x & 63;
    const int wv = threadIdx.x >> 6;
    const int kbase = ((lane >> 4) & 3) * 8;
    const int arow = r0 + wv * 16 + (lane & 15);
    const float* xrow = x + (size_t)arow * CIN;

    // x tile -> fp16 registers
    f16x8 a[8];
    #pragma unroll
    for (int kk = 0; kk < 8; ++kk) {
        const float4* xp = (const float4*)(xrow + kk * 32 + kbase);
        float4 x0 = xp[0], x1 = xp[1];
        float xs[8] = {x0.x, x0.y, x0.z, x0.w, x1.x, x1.y, x1.z, x1.w};
        #pragma unroll
        for (int e = 0; e < 8; ++e) a[kk][e] = (_Float16)xs[e];
    }
    __syncthreads();

    f32x4 acc[4] = {f32x4{0,0,0,0}, f32x4{0,0,0,0}, f32x4{0,0,0,0}, f32x4{0,0,0,0}};
    #pragma unroll
    for (int kk = 0; kk < 8; ++kk) {
        #pragma unroll
        for (int nt = 0; nt < 4; ++nt) {
            f16x8 b = *(const f16x8*)&wt[(lane & 15) + 16 * nt][kk * 32 + kbase];
            acc[nt] = MFMA_F16(a[kk], b, acc[nt]);
        }
    }

    const int rloc = wv * 16 + ((lane >> 4) & 3) * 4;   // local row base of frag
    if (m < 2) {
        // repack through LDS (reuse wt) -> coalesced 16B stores
        __syncthreads();                   // all wt fragment reads done
        _Float16* rp = &wt[0][0];          // viewed as [64][72]
        #pragma unroll
        for (int nt = 0; nt < 4; ++nt)
            #pragma unroll
            for (int r = 0; r < 4; ++r)
                rp[(rloc + r) * 72 + (lane & 15) + 16 * nt] = (_Float16)acc[nt][r];
        __syncthreads();
        _Float16* dst = (m == 0) ? k_ws : q_ws;
        const int row = threadIdx.x >> 3, c0 = (threadIdx.x & 7) * 8;
        #pragma unroll
        for (int h = 0; h < 2; ++h) {
            uint4 v = *(const uint4*)&rp[(row + 32 * h) * 72 + c0];
            *(uint4*)(dst + (size_t)(r0 + row + 32 * h) * CMID + c0) = v;
        }
    } else {
        const int rrow = r0 + rloc;
        const int b = rrow >> 12;
        const int n = rrow & (NPOS - 1);
        #pragma unroll
        for (int nt = 0; nt < 4; ++nt) {
            int cv = (lane & 15) + 16 * nt;
            union { __bf16 h[4]; uint2 u; } pk;
            #pragma unroll
            for (int r = 0; r < 4; ++r) pk.h[r] = (__bf16)acc[nt][r];
            *(uint2*)(vT_ws + ((size_t)b * CMID + cv) * NPOS + n) = pk.u;
        }
    }
}

// ---------------------------------------------------------------------------
// flash_kernel: streaming attention, 32x32 swapped-QK^T, in-register P.
// 8 waves x 32 i-rows (block=512 threads): aq/bv LDS reads depend only on
// j, so per-wave LDS traffic is unchanged vs fewer/wider waves, but
// resident waves/CU double -> 16 waves/CU (50% occ ceiling).
// Double-buffered tiles, issue-early/write-late staging. k pre-scaled by
// log2e -> p = exp2(s). Writes unnormalized partial numerators + den.
// grid (16, 8, NSPLIT): 256-row i-tile, batch, j-split.
// ---------------------------------------------------------------------------
__global__ __launch_bounds__(512, 4) void flash_kernel(
    const _Float16* __restrict__ k_ws,  // [32768][64]
    const _Float16* __restrict__ q_ws,  // [32768][64]
    const __bf16* __restrict__ vT_ws,   // [8][64][4096]
    __bf16* __restrict__ po,            // [NSPLIT][32768][64]
    float* __restrict__ pden)           // [NSPLIT][32768]
{
    const int b = blockIdx.y;
    const int i0 = blockIdx.x * 256;
    const int sblk = blockIdx.z;
    const int jbase = sblk * (NPOS / NSPLIT);
    const int lane = threadIdx.x & 63;
    const int wv = threadIdx.x >> 6;    // 0..7
    const int l31 = lane & 31;
    const int g = lane >> 5;

    __shared__ _Float16 qt[2][64][72];
    __shared__ __bf16 vt[2][64][72];

    // wave's 32 k-rows as B-fragments
    f16x8 kf[4];
    {
        const _Float16* kp =
            k_ws + ((size_t)(b * NPOS + i0 + wv * 32 + l31)) * CMID + g * 8;
        #pragma unroll
        for (int c = 0; c < 4; ++c) kf[c] = *(const f16x8*)(kp + c * 16);
    }

    f32x16 o0 = {0,0,0,0,0,0,0,0,0,0,0,0,0,0,0,0};
    f32x16 o1 = {0,0,0,0,0,0,0,0,0,0,0,0,0,0,0,0};
    float den = 0.f;

    // staging map: 512 threads x 16B = one 64x64 fp16/bf16 tile
    const int r = threadIdx.x >> 3, c0 = (threadIdx.x & 7) * 8;
    uint4 nq, nv;

    // prologue: tile 0
    {
        const _Float16* qs = q_ws + ((size_t)(b * NPOS + jbase + r)) * CMID + c0;
        nq = *(const uint4*)qs;
        const __bf16* vs = vT_ws + ((size_t)b * CMID + r) * NPOS + jbase + c0;
        nv = *(const uint4*)vs;
        *(uint4*)&qt[0][r][c0] = nq;
        *(uint4*)&vt[0][r][c0] = nv;
    }
    __syncthreads();

    const int NT = (NPOS / NSPLIT) / 64;  // 16
    for (int t = 0; t < NT; ++t) {
        const int cur = t & 1;
        if (t + 1 < NT) {   // issue next-tile loads early (latency hides under MFMA)
            int j1 = jbase + (t + 1) * 64;
            nq = *(const uint4*)(q_ws + ((size_t)(b * NPOS + j1 + r)) * CMID + c0);
            nv = *(const uint4*)(vT_ws + ((size_t)b * CMID + r) * NPOS + j1 + c0);
        }

        #pragma unroll
        for (int jj = 0; jj < 2; ++jj) {
            f16x8 aq[4];
            #pragma unroll
            for (int c = 0; c < 4; ++c)
                aq[c] = *(const f16x8*)&qt[cur][jj * 32 + l31][c * 16 + g * 8];
            bf16_8 bv00 = *(const bf16_8*)&vt[cur][l31][jj * 32 + g * 8];
            bf16_8 bv01 = *(const bf16_8*)&vt[cur][l31][jj * 32 + 16 + g * 8];
            bf16_8 bv10 = *(const bf16_8*)&vt[cur][32 + l31][jj * 32 + g * 8];
            bf16_8 bv11 = *(const bf16_8*)&vt[cur][32 + l31][jj * 32 + 16 + g * 8];

            f32x16 s = {0,0,0,0,0,0,0,0,0,0,0,0,0,0,0,0};
            s = MFMA32_F16(aq[0], kf[0], s);
            s = MFMA32_F16(aq[1], kf[1], s);
            s = MFMA32_F16(aq[2], kf[2], s);
            s = MFMA32_F16(aq[3], kf[3], s);

            unsigned pk[8];
            #pragma unroll
            for (int m = 0; m < 8; ++m) {
                float p0 = exp2f(s[2 * m]);
                float p1 = exp2f(s[2 * m + 1]);
                den += p0 + p1;
                union { __bf16 h[2]; unsigned u; } w;
                w.h[0] = (__bf16)p0; w.h[1] = (__bf16)p1;
                pk[m] = w.u;
            }
            swaplane32(pk[0], pk[2]); swaplane32(pk[1], pk[3]);
            swaplane32(pk[4], pk[6]); swaplane32(pk[5], pk[7]);
            union { unsigned u[4]; bf16_8 v; } pa0, pa1;
            pa0.u[0] = pk[0]; pa0.u[1] = pk[1]; pa0.u[2] = pk[2]; pa0.u[3] = pk[3];
            pa1.u[0] = pk[4]; pa1.u[1] = pk[5]; pa1.u[2] = pk[6]; pa1.u[3] = pk[7];

            o0 = MFMA32_BF(pa0.v, bv00, o0);
            o0 = MFMA32_BF(pa1.v, bv01, o0);
            o1 = MFMA32_BF(pa0.v, bv10, o1);
            o1 = MFMA32_BF(pa1.v, bv11, o1);
        }

        if (t + 1 < NT) {   // write-late into the other buffer
            const int nb = cur ^ 1;
            *(uint4*)&qt[nb][r][c0] = nq;
            *(uint4*)&vt[nb][r][c0] = nv;
        }
        __syncthreads();
    }

    den += __shfl_xor(den, 32);

    const size_t rowb = (size_t)b * NPOS + i0 + wv * 32;
    if (lane < 32)
        pden[(size_t)sblk * NROWS + rowb + lane] = den;

    #pragma unroll
    for (int reg = 0; reg < 16; ++reg) {
        int il = (reg & 3) + 8 * (reg >> 2) + 4 * g;
        size_t base = ((size_t)sblk * NROWS + rowb + il) * CMID + l31;
        po[base]      = (__bf16)o0[reg];
        po[base + 32] = (__bf16)o1[reg];
    }
}

// ---------------------------------------------------------------------------
// out_kernel: combine j-split partials (normalize, bf16) + MFMA attn @ Wo
// + fused BatchNorm. Wo B-fragments loaded straight from global (L2-hot).
// grid 2048, block 256 (4 waves, wave wv owns output cols wv*64..+63).
// ---------------------------------------------------------------------------
__global__ __launch_bounds__(256) void out_kernel(
    const __bf16* __restrict__ po,      // [NSPLIT][32768][64]
    const float* __restrict__ pden,     // [NSPLIT][32768]
    const float* __restrict__ Wo,       // [64][256]
    const float* __restrict__ gamma, const float* __restrict__ beta,
    const float* __restrict__ mmean, const float* __restrict__ mvar,
    float* __restrict__ out)            // [32768][256]
{
    const int r0 = blockIdx.x * 16;
    const int t = threadIdx.x;
    const int lane = t & 63;
    const int wv = t >> 6;
    const int n0 = wv * 64;

    __shared__ __bf16 at[16][72];
    __shared__ float dinv[16];

    // Wo B-fragments from global, bf16 cast (issued early, L2-hot)
    bf16_8 wb[4][2];
    #pragma unroll
    for (int nt = 0; nt < 4; ++nt) {
        int col = n0 + nt * 16 + (lane & 15);
        #pragma unroll
        for (int ch = 0; ch < 2; ++ch)
            #pragma unroll
            for (int e = 0; e < 8; ++e)
                wb[nt][ch][e] = (__bf16)Wo[(ch * 32 + (lane >> 4) * 8 + e) * OC + col];
    }

    if (t < 16) {
        float d = 0.f;
        #pragma unroll
        for (int s = 0; s < NSPLIT; ++s) d += pden[(size_t)s * NROWS + r0 + t];
        dinv[t] = 1.0f / d;
    }
    __syncthreads();

    for (int idx = t; idx < 16 * 64; idx += 256) {
        int rr = idx >> 6, c = idx & 63;
        float sum = 0.f;
        #pragma unroll
        for (int s = 0; s < NSPLIT; ++s)
            sum += (float)po[((size_t)s * NROWS + r0 + rr) * CMID + c];
        at[rr][c] = (__bf16)(sum * dinv[rr]);
    }
    __syncthreads();

    bf16_8 a0 = *(const bf16_8*)&at[lane & 15][(lane >> 4) * 8];
    bf16_8 a1 = *(const bf16_8*)&at[lane & 15][32 + (lane >> 4) * 8];

    #pragma unroll
    for (int nt = 0; nt < 4; ++nt) {
        int col = n0 + nt * 16 + (lane & 15);
        f32x4 acc = {0.f, 0.f, 0.f, 0.f};
        acc = MFMA_BF(a0, wb[nt][0], acc);
        acc = MFMA_BF(a1, wb[nt][1], acc);
        float sc = gamma[col] * rsqrtf(mvar[col] + 1e-3f);
        float sh = beta[col] - mmean[col] * sc;
        int rl = (lane >> 4) * 4;
        #pragma unroll
        for (int rr = 0; rr < 4; ++rr)
            out[(size_t)(r0 + rl + rr) * OC + col] = acc[rr] * sc + sh;
    }
}

// ---------------------------------------------------------------------------
extern "C" void kernel_launch(void* const* d_in, const int* in_sizes, int n_in,
                              void* d_out, int out_size, void* d_ws, size_t ws_size,
                              hipStream_t stream) {
    const float* x     = (const float*)d_in[0];
    const float* Wk    = (const float*)d_in[1];
    const float* Wq    = (const float*)d_in[2];
    const float* Wv    = (const float*)d_in[3];
    const float* Wo    = (const float*)d_in[4];
    const float* gamma = (const float*)d_in[5];
    const float* beta  = (const float*)d_in[6];
    const float* mmean = (const float*)d_in[7];
    const float* mvar  = (const float*)d_in[8];
    float* out = (float*)d_out;

    // k/q/vT live in d_out (33.5 MB): dead before out_kernel writes out.
    char* ob = (char*)d_out;
    const size_t MB4 = (size_t)NROWS * CMID * 2;   // 4 MiB
    _Float16* k_ws = (_Float16*)ob;                // 4 MiB
    _Float16* q_ws = (_Float16*)(ob + MB4);        // 4 MiB
    __bf16*   vT   = (__bf16*)(ob + 2 * MB4);      // 4 MiB

    __bf16* po   = (__bf16*)d_ws;                                // 16 MiB
    float*  pden = (float*)((char*)d_ws + (size_t)NSPLIT * MB4); // 512 KiB

    proj_kernel<<<dim3(512, 3), 256, 0, stream>>>(x, Wk, Wq, Wv, k_ws, q_ws, vT);
    flash_kernel<<<dim3(16, 8, NSPLIT), 512, 0, stream>>>(k_ws, q_ws, vT, po, pden);
    out_kernel<<<2048, 256, 0, stream>>>(po, pden, Wo, gamma, beta, mmean, mvar, out);
}